// Round 3
// baseline (211.304 us; speedup 1.0000x reference)
//
#include <hip/hip_runtime.h>
#include <stdint.h>

#define B_ 4
#define N_ 2048
#define T_ 8
#define NL_ 64
#define DIM_ 1024
#define H_ 16
#define HD_ 64
#define TN_ (T_*NL_)   // 512

typedef __bf16 bf16x8 __attribute__((ext_vector_type(8)));
typedef float f32x4 __attribute__((ext_vector_type(4)));

__device__ __forceinline__ float b2f(unsigned short x) {
  union { uint32_t u; float f; } v; v.u = ((uint32_t)x) << 16; return v.f;
}
__device__ __forceinline__ unsigned short f2b(float f) {
  union { float f; uint32_t u; } v; v.f = f;
  uint32_t r = v.u + 0x7FFFu + ((v.u >> 16) & 1u);
  return (unsigned short)(r >> 16);
}

// direct HBM->LDS DMA, 16B per lane (global_load_lds_dwordx4).
// LDS dest must be linear in lane id within the wave (m104 contract).
__device__ __forceinline__ void gload_lds16(const unsigned short* g, unsigned short* l) {
  __builtin_amdgcn_global_load_lds(
      (const __attribute__((address_space(1))) uint32_t*)g,
      (__attribute__((address_space(3))) uint32_t*)l, 16, 0, 0);
}

// ---------------- fp32-vs-bf16 storage detection ----------------
__global__ void detect_kernel(const unsigned short* __restrict__ text, int* __restrict__ flag) {
  int t = threadIdx.x;
  int bad = 0;
  #pragma unroll
  for (int i = 0; i < 16; i++) {
    unsigned short w = text[t * 16 + i];
    int e = (w >> 7) & 0xFF;
    if (e != 0 && (e < 90 || e > 150)) bad++;
  }
  __shared__ int red[256];
  red[t] = bad;
  __syncthreads();
  for (int o = 128; o > 0; o >>= 1) { if (t < o) red[t] += red[t + o]; __syncthreads(); }
  if (t == 0) flag[0] = (red[0] > 256) ? 1 : 0;   // 1 = fp32 storage
}

// ---------------- merged cast to bf16: media (2M elems) + bo (1K elems) --------
__global__ void cast2_kernel(const void* __restrict__ media, unsigned short* __restrict__ mb,
                             const void* __restrict__ bo, unsigned short* __restrict__ bob,
                             const int* __restrict__ flag) {
  const int N4M = (B_*T_*NL_*DIM_) / 4;   // 524288
  int i = blockIdx.x * 256 + threadIdx.x;
  bool isf = (*flag != 0);
  if (i < N4M) {
    ushort4 o;
    if (isf) {
      float4 v = ((const float4*)media)[i];
      o.x = f2b(v.x); o.y = f2b(v.y); o.z = f2b(v.z); o.w = f2b(v.w);
    } else {
      o = ((const ushort4*)media)[i];
    }
    ((ushort4*)mb)[i] = o;
  } else {
    int j = i - N4M;
    if (j < DIM_/4) {
      ushort4 o;
      if (isf) {
        float4 v = ((const float4*)bo)[j];
        o.x = f2b(v.x); o.y = f2b(v.y); o.z = f2b(v.z); o.w = f2b(v.w);
      } else {
        o = ((const ushort4*)bo)[j];
      }
      ((ushort4*)bob)[j] = o;
    }
  }
}

// ---------------- text_times: detect storage (bool-bytes vs int32) + block scan ----
__global__ void times_kernel(const void* __restrict__ locs, int* __restrict__ tt) {
  int b = blockIdx.x, t = threadIdx.x;
  const unsigned char* p8 = (const unsigned char*)locs;
  const int* p32 = (const int*)locs;
  __shared__ int red[256];
  int cnt = 0;
  for (int i = t; i < B_*N_; i += 256) cnt += (p8[i] != 0) ? 1 : 0;
  red[t] = cnt;
  __syncthreads();
  for (int off = 128; off > 0; off >>= 1) {
    if (t < off) red[t] += red[t + off];
    __syncthreads();
  }
  int total = red[0];
  __syncthreads();
  bool isb = (total >= 2 * T_);
  int x[8];
  int base = b * N_ + t * 8;
  if (isb) {
    #pragma unroll
    for (int i = 0; i < 8; i++) x[i] = (int)(p8[base + i] != 0);
  } else {
    #pragma unroll
    for (int i = 0; i < 8; i++) x[i] = (int)(p32[base + i] != 0);
  }
  #pragma unroll
  for (int i = 1; i < 8; i++) x[i] += x[i-1];
  int tot = x[7];
  red[t] = tot;
  __syncthreads();
  for (int off = 1; off < 256; off <<= 1) {
    int v = (t >= off) ? red[t - off] : 0;
    __syncthreads();
    red[t] += v;
    __syncthreads();
  }
  int excl = red[t] - tot;
  #pragma unroll
  for (int i = 0; i < 8; i++) tt[base + i] = excl + x[i];
}

// ---------------- LayerNorm (row per block), dtype-flag aware ----------------
__global__ void ln_kernel(const void* __restrict__ x,
                          const void* __restrict__ g,
                          const void* __restrict__ bta,
                          unsigned short* __restrict__ y,
                          const int* __restrict__ flag) {
  int row = blockIdx.x;
  int t = threadIdx.x;
  bool isf = (*flag != 0);
  float f0, f1, f2, f3, g0, g1, g2, g3, c0, c1, c2, c3;
  if (isf) {
    float4 xv = ((const float4*)x)[(size_t)row * (DIM_/4) + t];
    f0 = xv.x; f1 = xv.y; f2 = xv.z; f3 = xv.w;
    float4 gv = ((const float4*)g)[t];
    g0 = gv.x; g1 = gv.y; g2 = gv.z; g3 = gv.w;
    float4 bv = ((const float4*)bta)[t];
    c0 = bv.x; c1 = bv.y; c2 = bv.z; c3 = bv.w;
  } else {
    ushort4 xv = ((const ushort4*)x)[(size_t)row * (DIM_/4) + t];
    f0 = b2f(xv.x); f1 = b2f(xv.y); f2 = b2f(xv.z); f3 = b2f(xv.w);
    ushort4 gv = ((const ushort4*)g)[t];
    g0 = b2f(gv.x); g1 = b2f(gv.y); g2 = b2f(gv.z); g3 = b2f(gv.w);
    ushort4 bv = ((const ushort4*)bta)[t];
    c0 = b2f(bv.x); c1 = b2f(bv.y); c2 = b2f(bv.z); c3 = b2f(bv.w);
  }
  float s  = f0 + f1 + f2 + f3;
  float s2 = f0*f0 + f1*f1 + f2*f2 + f3*f3;
  for (int off = 32; off > 0; off >>= 1) { s += __shfl_xor(s, off); s2 += __shfl_xor(s2, off); }
  __shared__ float sm[8];
  int wave = t >> 6, lane = t & 63;
  if (lane == 0) { sm[wave] = s; sm[wave + 4] = s2; }
  __syncthreads();
  float ts  = sm[0] + sm[1] + sm[2] + sm[3];
  float ts2 = sm[4] + sm[5] + sm[6] + sm[7];
  float mean = ts * (1.0f / DIM_);
  float var  = ts2 * (1.0f / DIM_) - mean * mean;
  float rs = rsqrtf(var + 1e-5f);
  ushort4 o;
  o.x = f2b((f0 - mean) * rs * g0 + c0);
  o.y = f2b((f1 - mean) * rs * g1 + c1);
  o.z = f2b((f2 - mean) * rs * g2 + c2);
  o.w = f2b((f3 - mean) * rs * g3 + c3);
  ((ushort4*)(y + (size_t)row * DIM_))[t] = o;
}

// ---------------- merged transpose+cast of all 3 weights (grid.z selects) ------
__global__ void transpose3_kernel(const void* __restrict__ wq, unsigned short* __restrict__ wqt,
                                  const void* __restrict__ wkv, unsigned short* __restrict__ wkvt,
                                  const void* __restrict__ wo, unsigned short* __restrict__ wot,
                                  const int* __restrict__ flag) {
  const void* src; unsigned short* dst; int C;
  if (blockIdx.z == 0)      { src = wq;  dst = wqt;  C = 1024; }
  else if (blockIdx.z == 1) { src = wkv; dst = wkvt; C = 2048; }
  else                      { src = wo;  dst = wot;  C = 1024; }
  const int R = 1024;
  int bx = blockIdx.x * 32, by = blockIdx.y * 32;
  if (bx >= C) return;
  __shared__ unsigned short tile[32][33];
  int x = threadIdx.x, y = threadIdx.y;
  if (*flag) {
    const float* s = (const float*)src;
    for (int i = y; i < 32; i += 8) tile[i][x] = f2b(s[(size_t)(by + i) * C + bx + x]);
  } else {
    const unsigned short* s = (const unsigned short*)src;
    for (int i = y; i < 32; i += 8) tile[i][x] = s[(size_t)(by + i) * C + bx + x];
  }
  __syncthreads();
  for (int i = y; i < 32; i += 8) dst[(size_t)(bx + i) * R + by + x] = tile[x][i];
}

// ---------------- 128x128 MFMA GEMM core: global_load_lds + double-buffer ----
// C[M,N] = A[M,K] @ Bt[N,K]^T (+bias). 256 threads, 4 waves in 2x2 over the tile.
// 2-phase pipeline (T3-lite): DMA of tile k+1 is issued BEFORE the ds_read+MFMA
// of tile k, so HBM/L2 latency overlaps compute; ONE barrier per K-step (its
// vmcnt(0) drain completes the prefetch). LDS dest linear in lane id (m104).
__device__ __forceinline__ void gemm128_core(const unsigned short* __restrict__ A,
                                             const unsigned short* __restrict__ Bt,
                                             unsigned short* __restrict__ C,
                                             float* __restrict__ Cf,
                                             const unsigned short* __restrict__ bias,
                                             int bid, int mtiles, int M, int N, int K,
                                             bool f32o, int t) {
  __shared__ unsigned short As[2][128][32];
  __shared__ unsigned short Bs[2][128][32];
  int m0 = (bid % mtiles) * 128, n0 = (bid / mtiles) * 128;
  int wave = t >> 6, lane = t & 63;
  int wr = wave >> 1, wc = wave & 1;
  f32x4 acc[4][4];
  #pragma unroll
  for (int i = 0; i < 4; i++)
    #pragma unroll
    for (int j = 0; j < 4; j++)
      #pragma unroll
      for (int r = 0; r < 4; r++) acc[i][j][r] = 0.f;
  int lr = lane & 15, lk = (lane >> 4) * 8;
  // per-thread staging coordinates (chunk c = t, t+256; 8 bf16 per chunk)
  int row0 = t >> 2,        kc0 = (t & 3) * 8;
  int row1 = (t + 256) >> 2, kc1 = ((t + 256) & 3) * 8;
  const unsigned short* a0 = A  + (size_t)(m0 + row0) * K + kc0;
  const unsigned short* a1 = A  + (size_t)(m0 + row1) * K + kc1;
  const unsigned short* b0 = Bt + (size_t)(n0 + row0) * K + kc0;
  const unsigned short* b1 = Bt + (size_t)(n0 + row1) * K + kc1;
  // prologue: stage tile 0 into buffer 0
  gload_lds16(a0, &As[0][row0][kc0]);
  gload_lds16(a1, &As[0][row1][kc1]);
  gload_lds16(b0, &Bs[0][row0][kc0]);
  gload_lds16(b1, &Bs[0][row1][kc1]);
  __syncthreads();
  int cur = 0;
  for (int k0 = 0; k0 < K; k0 += 32) {
    int nxt = cur ^ 1;
    if (k0 + 32 < K) {          // issue next-tile DMA before compute
      gload_lds16(a0 + k0 + 32, &As[nxt][row0][kc0]);
      gload_lds16(a1 + k0 + 32, &As[nxt][row1][kc1]);
      gload_lds16(b0 + k0 + 32, &Bs[nxt][row0][kc0]);
      gload_lds16(b1 + k0 + 32, &Bs[nxt][row1][kc1]);
    }
    bf16x8 af[4], bfr[4];
    #pragma unroll
    for (int i = 0; i < 4; i++) af[i]  = *(const bf16x8*)(&As[cur][wr * 64 + i * 16 + lr][lk]);
    #pragma unroll
    for (int j = 0; j < 4; j++) bfr[j] = *(const bf16x8*)(&Bs[cur][wc * 64 + j * 16 + lr][lk]);
    #pragma unroll
    for (int i = 0; i < 4; i++)
      #pragma unroll
      for (int j = 0; j < 4; j++)
        acc[i][j] = __builtin_amdgcn_mfma_f32_16x16x32_bf16(af[i], bfr[j], acc[i][j], 0, 0, 0);
    __syncthreads();            // drains vmcnt(0): prefetch landed, buffers swap
    cur = nxt;
  }
  int rbase = (lane >> 4) * 4;
  int cbase = lane & 15;
  #pragma unroll
  for (int i = 0; i < 4; i++) {
    #pragma unroll
    for (int j = 0; j < 4; j++) {
      int row = m0 + wr * 64 + i * 16 + rbase;
      int col = n0 + wc * 64 + j * 16 + cbase;
      float bv = bias ? b2f(bias[col]) : 0.f;
      if (f32o) {
        #pragma unroll
        for (int r = 0; r < 4; r++)
          Cf[(size_t)(row + r) * N + col] = acc[i][j][r] + bv;
      } else {
        #pragma unroll
        for (int r = 0; r < 4; r++)
          C[(size_t)(row + r) * N + col] = f2b(acc[i][j][r] + bv);
      }
    }
  }
}

// fused q-GEMM (blocks [0,512): 64 mtiles x 8 ntiles) +
//       kv-GEMM (blocks [512,768): 16 mtiles x 16 ntiles = 256 blocks)
__global__ __launch_bounds__(256) void gemm_qkv(const unsigned short* __restrict__ tn,
                                                const unsigned short* __restrict__ wqt,
                                                unsigned short* __restrict__ qb,
                                                const unsigned short* __restrict__ mb,
                                                const unsigned short* __restrict__ wkvt,
                                                unsigned short* __restrict__ kvb) {
  int bid = blockIdx.x;
  if (bid < 512)
    gemm128_core(tn, wqt, qb, nullptr, nullptr, bid, 64, B_ * N_, DIM_, DIM_, false, threadIdx.x);
  else
    gemm128_core(mb, wkvt, kvb, nullptr, nullptr, bid - 512, 16, B_ * TN_, 2 * DIM_, DIM_, false, threadIdx.x);
}

__global__ __launch_bounds__(256) void gemm_out(const unsigned short* __restrict__ ao,
                                                const unsigned short* __restrict__ wot,
                                                unsigned short* __restrict__ C,
                                                float* __restrict__ Cf,
                                                const unsigned short* __restrict__ bias,
                                                const int* __restrict__ flag) {
  bool f32o = (*flag != 0);
  gemm128_core(ao, wot, C, Cf, bias, blockIdx.x, 64, B_ * N_, DIM_, DIM_, f32o, threadIdx.x);
}

// ---------------- MFMA attention: 1 wave per (b, 64-row tile, head) -------------
__global__ __launch_bounds__(64) void attn_mfma(const unsigned short* __restrict__ q,
                                                const unsigned short* __restrict__ kv,
                                                const int* __restrict__ tt,
                                                unsigned short* __restrict__ ao) {
  __shared__ unsigned short Vt[64][72];   // V^T [d][key]
  __shared__ unsigned short Ps[64][72];   // P [q][key]; reused as O staging
  int bid = blockIdx.x;
  int h  = bid & 15;
  int nt = (bid >> 4) & 31;
  int b  = bid >> 9;
  int bn0 = b * N_ + nt * 64;
  int lane = threadIdx.x & 63;
  int lr = lane & 15;
  int g  = lane >> 4;
  int g8 = g * 8;

  int tv = tt[bn0];             // tile-uniform by mask structure
  float vmul = (tv >= 1 && tv <= T_) ? 1.f : 0.f;
  int tvc = tv < 1 ? 1 : (tv > T_ ? T_ : tv);
  int kvrow0 = b * TN_ + (tvc - 1) * NL_;

  const unsigned short* vbase = kv + (size_t)kvrow0 * (2 * DIM_) + DIM_ + h * HD_;
  #pragma unroll
  for (int d0 = 0; d0 < 64; d0 += 8) {
    uint4 v = *(const uint4*)(vbase + (size_t)lane * (2 * DIM_) + d0);
    Vt[d0 + 0][lane] = (unsigned short)(v.x & 0xffff);
    Vt[d0 + 1][lane] = (unsigned short)(v.x >> 16);
    Vt[d0 + 2][lane] = (unsigned short)(v.y & 0xffff);
    Vt[d0 + 3][lane] = (unsigned short)(v.y >> 16);
    Vt[d0 + 4][lane] = (unsigned short)(v.z & 0xffff);
    Vt[d0 + 5][lane] = (unsigned short)(v.z >> 16);
    Vt[d0 + 6][lane] = (unsigned short)(v.w & 0xffff);
    Vt[d0 + 7][lane] = (unsigned short)(v.w >> 16);
  }

  f32x4 S[4][4];
  #pragma unroll
  for (int i = 0; i < 4; i++)
    #pragma unroll
    for (int j = 0; j < 4; j++)
      #pragma unroll
      for (int r = 0; r < 4; r++) S[i][j][r] = 0.f;
  #pragma unroll
  for (int ks = 0; ks < 2; ks++) {
    bf16x8 aQ[4], bK[4];
    #pragma unroll
    for (int mi = 0; mi < 4; mi++)
      aQ[mi] = *(const bf16x8*)(q + (size_t)(bn0 + mi * 16 + lr) * DIM_ + h * HD_ + ks * 32 + g8);
    #pragma unroll
    for (int ni = 0; ni < 4; ni++)
      bK[ni] = *(const bf16x8*)(kv + (size_t)(kvrow0 + ni * 16 + lr) * (2 * DIM_) + h * HD_ + ks * 32 + g8);
    #pragma unroll
    for (int mi = 0; mi < 4; mi++)
      #pragma unroll
      for (int ni = 0; ni < 4; ni++)
        S[mi][ni] = __builtin_amdgcn_mfma_f32_16x16x32_bf16(aQ[mi], bK[ni], S[mi][ni], 0, 0, 0);
  }

  #pragma unroll
  for (int mi = 0; mi < 4; mi++) {
    #pragma unroll
    for (int r = 0; r < 4; r++) {
      float mx = fmaxf(fmaxf(S[mi][0][r], S[mi][1][r]), fmaxf(S[mi][2][r], S[mi][3][r]));
      mx = fmaxf(mx, __shfl_xor(mx, 1));
      mx = fmaxf(mx, __shfl_xor(mx, 2));
      mx = fmaxf(mx, __shfl_xor(mx, 4));
      mx = fmaxf(mx, __shfl_xor(mx, 8));
      float e0 = __expf(S[mi][0][r] - mx);
      float e1 = __expf(S[mi][1][r] - mx);
      float e2 = __expf(S[mi][2][r] - mx);
      float e3 = __expf(S[mi][3][r] - mx);
      float sum = e0 + e1 + e2 + e3;
      sum += __shfl_xor(sum, 1);
      sum += __shfl_xor(sum, 2);
      sum += __shfl_xor(sum, 4);
      sum += __shfl_xor(sum, 8);
      float inv = 1.f / sum;
      int qrow = mi * 16 + g * 4 + r;
      Ps[qrow][ 0 + lr] = f2b(e0 * inv);
      Ps[qrow][16 + lr] = f2b(e1 * inv);
      Ps[qrow][32 + lr] = f2b(e2 * inv);
      Ps[qrow][48 + lr] = f2b(e3 * inv);
    }
  }
  __syncthreads();

  f32x4 O[4][4];
  #pragma unroll
  for (int i = 0; i < 4; i++)
    #pragma unroll
    for (int j = 0; j < 4; j++)
      #pragma unroll
      for (int r = 0; r < 4; r++) O[i][j][r] = 0.f;
  #pragma unroll
  for (int ks = 0; ks < 2; ks++) {
    bf16x8 aP[4], bV[4];
    #pragma unroll
    for (int mi = 0; mi < 4; mi++)
      aP[mi] = *(const bf16x8*)(&Ps[mi * 16 + lr][ks * 32 + g8]);
    #pragma unroll
    for (int ni = 0; ni < 4; ni++)
      bV[ni] = *(const bf16x8*)(&Vt[ni * 16 + lr][ks * 32 + g8]);
    #pragma unroll
    for (int mi = 0; mi < 4; mi++)
      #pragma unroll
      for (int ni = 0; ni < 4; ni++)
        O[mi][ni] = __builtin_amdgcn_mfma_f32_16x16x32_bf16(aP[mi], bV[ni], O[mi][ni], 0, 0, 0);
  }
  __syncthreads();

  #pragma unroll
  for (int mi = 0; mi < 4; mi++)
    #pragma unroll
    for (int ni = 0; ni < 4; ni++)
      #pragma unroll
      for (int r = 0; r < 4; r++)
        Ps[mi * 16 + g * 4 + r][ni * 16 + lr] = f2b(O[mi][ni][r] * vmul);
  __syncthreads();
  uint4* dst = (uint4*)(ao + (size_t)(bn0 + lane) * DIM_ + h * HD_);
  #pragma unroll
  for (int c = 0; c < 8; c++)
    dst[c] = *(const uint4*)(&Ps[lane][c * 8]);
}

extern "C" void kernel_launch(void* const* d_in, const int* in_sizes, int n_in,
                              void* d_out, int out_size, void* d_ws, size_t ws_size,
                              hipStream_t stream) {
  const void* text = d_in[0];
  const void* media = d_in[1];
  const void* mloc = d_in[2];
  const void* wq  = d_in[3];
  const void* wkv = d_in[4];
  const void* wo  = d_in[5];
  const void* bo  = d_in[6];
  const void* lng = d_in[7];
  const void* lnb = d_in[8];

  char* ws = (char*)d_ws;
  const size_t OFF_FLAG = (size_t)32 << 10;
  const size_t OFF_TN   = (size_t)64 << 10;
  const size_t OFF_WQT  = OFF_TN  + ((size_t)16 << 20) + ((size_t)64 << 10);
  const size_t OFF_WKVT = OFF_WQT + ((size_t)2 << 20);
  const size_t OFF_WOT  = OFF_WKVT + ((size_t)4 << 20);
  const size_t OFF_KV   = OFF_WOT + ((size_t)2 << 20);
  const size_t OFF_MB   = OFF_KV  + ((size_t)8 << 20);
  const size_t OFF_BO   = OFF_MB  + ((size_t)4 << 20);
  const size_t OFF_QB   = OFF_BO  + ((size_t)64 << 10);
  int* tt               = (int*)(ws + 0);
  int* flag             = (int*)(ws + OFF_FLAG);
  unsigned short* tn    = (unsigned short*)(ws + OFF_TN);
  unsigned short* ao    = tn;                               // reuse after q GEMM
  unsigned short* wqt   = (unsigned short*)(ws + OFF_WQT);
  unsigned short* wkvt  = (unsigned short*)(ws + OFF_WKVT);
  unsigned short* wot   = (unsigned short*)(ws + OFF_WOT);
  unsigned short* kvb   = (unsigned short*)(ws + OFF_KV);
  unsigned short* mb    = (unsigned short*)(ws + OFF_MB);
  unsigned short* bob   = (unsigned short*)(ws + OFF_BO);
  unsigned short* qb    = (unsigned short*)(ws + OFF_QB);

  detect_kernel<<<1, 256, 0, stream>>>((const unsigned short*)text, flag);
  times_kernel<<<B_, 256, 0, stream>>>(mloc, tt);
  ln_kernel<<<B_ * N_, 256, 0, stream>>>(text, lng, lnb, tn, flag);
  cast2_kernel<<<2049, 256, 0, stream>>>(media, mb, bo, bob, flag);
  transpose3_kernel<<<dim3(64, 32, 3), dim3(32, 8), 0, stream>>>(wq, wqt, wkv, wkvt, wo, wot, flag);

  // fused q (512 blocks, m-fastest) + kv (256 blocks) 128^2 dbuf GEMM
  gemm_qkv<<<768, 256, 0, stream>>>(tn, wqt, qb, mb, wkvt, kvb);
  // attention: 1 wave per (b, 64-row tile, head)
  attn_mfma<<<B_ * (N_/64) * H_, 64, 0, stream>>>(qb, kvb, tt, ao);
  // out = ao @ wo + bo (fp32 out if inputs fp32)
  gemm_out<<<512, 256, 0, stream>>>(ao, wot, (unsigned short*)d_out, (float*)d_out, bob, flag);
}

// Round 4
// 206.394 us; speedup vs baseline: 1.0238x; 1.0238x over previous
//
#include <hip/hip_runtime.h>
#include <stdint.h>

#define B_ 4
#define N_ 2048
#define T_ 8
#define NL_ 64
#define DIM_ 1024
#define H_ 16
#define HD_ 64
#define TN_ (T_*NL_)   // 512

typedef __bf16 bf16x8 __attribute__((ext_vector_type(8)));
typedef float f32x4 __attribute__((ext_vector_type(4)));

__device__ __forceinline__ float b2f(unsigned short x) {
  union { uint32_t u; float f; } v; v.u = ((uint32_t)x) << 16; return v.f;
}
__device__ __forceinline__ unsigned short f2b(float f) {
  union { float f; uint32_t u; } v; v.f = f;
  uint32_t r = v.u + 0x7FFFu + ((v.u >> 16) & 1u);
  return (unsigned short)(r >> 16);
}

// direct HBM->LDS DMA, 16B per lane (global_load_lds_dwordx4).
// LDS dest must be linear in lane id within the wave (m104 contract).
__device__ __forceinline__ void gload_lds16(const unsigned short* g, unsigned short* l) {
  __builtin_amdgcn_global_load_lds(
      (const __attribute__((address_space(1))) uint32_t*)g,
      (__attribute__((address_space(3))) uint32_t*)l, 16, 0, 0);
}

// ---------------- fp32-vs-bf16 storage detection ----------------
__global__ void detect_kernel(const unsigned short* __restrict__ text, int* __restrict__ flag) {
  int t = threadIdx.x;
  int bad = 0;
  #pragma unroll
  for (int i = 0; i < 16; i++) {
    unsigned short w = text[t * 16 + i];
    int e = (w >> 7) & 0xFF;
    if (e != 0 && (e < 90 || e > 150)) bad++;
  }
  __shared__ int red[256];
  red[t] = bad;
  __syncthreads();
  for (int o = 128; o > 0; o >>= 1) { if (t < o) red[t] += red[t + o]; __syncthreads(); }
  if (t == 0) flag[0] = (red[0] > 256) ? 1 : 0;   // 1 = fp32 storage
}

// ---------------- merged cast to bf16: media (2M elems) + bo (1K elems) --------
__global__ void cast2_kernel(const void* __restrict__ media, unsigned short* __restrict__ mb,
                             const void* __restrict__ bo, unsigned short* __restrict__ bob,
                             const int* __restrict__ flag) {
  const int N4M = (B_*T_*NL_*DIM_) / 4;   // 524288
  int i = blockIdx.x * 256 + threadIdx.x;
  bool isf = (*flag != 0);
  if (i < N4M) {
    ushort4 o;
    if (isf) {
      float4 v = ((const float4*)media)[i];
      o.x = f2b(v.x); o.y = f2b(v.y); o.z = f2b(v.z); o.w = f2b(v.w);
    } else {
      o = ((const ushort4*)media)[i];
    }
    ((ushort4*)mb)[i] = o;
  } else {
    int j = i - N4M;
    if (j < DIM_/4) {
      ushort4 o;
      if (isf) {
        float4 v = ((const float4*)bo)[j];
        o.x = f2b(v.x); o.y = f2b(v.y); o.z = f2b(v.z); o.w = f2b(v.w);
      } else {
        o = ((const ushort4*)bo)[j];
      }
      ((ushort4*)bob)[j] = o;
    }
  }
}

// ---------------- text_times: detect storage (bool-bytes vs int32) + block scan ----
__global__ void times_kernel(const void* __restrict__ locs, int* __restrict__ tt) {
  int b = blockIdx.x, t = threadIdx.x;
  const unsigned char* p8 = (const unsigned char*)locs;
  const int* p32 = (const int*)locs;
  __shared__ int red[256];
  int cnt = 0;
  for (int i = t; i < B_*N_; i += 256) cnt += (p8[i] != 0) ? 1 : 0;
  red[t] = cnt;
  __syncthreads();
  for (int off = 128; off > 0; off >>= 1) {
    if (t < off) red[t] += red[t + off];
    __syncthreads();
  }
  int total = red[0];
  __syncthreads();
  bool isb = (total >= 2 * T_);
  int x[8];
  int base = b * N_ + t * 8;
  if (isb) {
    #pragma unroll
    for (int i = 0; i < 8; i++) x[i] = (int)(p8[base + i] != 0);
  } else {
    #pragma unroll
    for (int i = 0; i < 8; i++) x[i] = (int)(p32[base + i] != 0);
  }
  #pragma unroll
  for (int i = 1; i < 8; i++) x[i] += x[i-1];
  int tot = x[7];
  red[t] = tot;
  __syncthreads();
  for (int off = 1; off < 256; off <<= 1) {
    int v = (t >= off) ? red[t - off] : 0;
    __syncthreads();
    red[t] += v;
    __syncthreads();
  }
  int excl = red[t] - tot;
  #pragma unroll
  for (int i = 0; i < 8; i++) tt[base + i] = excl + x[i];
}

// ---------------- LayerNorm (row per block), dtype-flag aware ----------------
__global__ void ln_kernel(const void* __restrict__ x,
                          const void* __restrict__ g,
                          const void* __restrict__ bta,
                          unsigned short* __restrict__ y,
                          const int* __restrict__ flag) {
  int row = blockIdx.x;
  int t = threadIdx.x;
  bool isf = (*flag != 0);
  float f0, f1, f2, f3, g0, g1, g2, g3, c0, c1, c2, c3;
  if (isf) {
    float4 xv = ((const float4*)x)[(size_t)row * (DIM_/4) + t];
    f0 = xv.x; f1 = xv.y; f2 = xv.z; f3 = xv.w;
    float4 gv = ((const float4*)g)[t];
    g0 = gv.x; g1 = gv.y; g2 = gv.z; g3 = gv.w;
    float4 bv = ((const float4*)bta)[t];
    c0 = bv.x; c1 = bv.y; c2 = bv.z; c3 = bv.w;
  } else {
    ushort4 xv = ((const ushort4*)x)[(size_t)row * (DIM_/4) + t];
    f0 = b2f(xv.x); f1 = b2f(xv.y); f2 = b2f(xv.z); f3 = b2f(xv.w);
    ushort4 gv = ((const ushort4*)g)[t];
    g0 = b2f(gv.x); g1 = b2f(gv.y); g2 = b2f(gv.z); g3 = b2f(gv.w);
    ushort4 bv = ((const ushort4*)bta)[t];
    c0 = b2f(bv.x); c1 = b2f(bv.y); c2 = b2f(bv.z); c3 = b2f(bv.w);
  }
  float s  = f0 + f1 + f2 + f3;
  float s2 = f0*f0 + f1*f1 + f2*f2 + f3*f3;
  for (int off = 32; off > 0; off >>= 1) { s += __shfl_xor(s, off); s2 += __shfl_xor(s2, off); }
  __shared__ float sm[8];
  int wave = t >> 6, lane = t & 63;
  if (lane == 0) { sm[wave] = s; sm[wave + 4] = s2; }
  __syncthreads();
  float ts  = sm[0] + sm[1] + sm[2] + sm[3];
  float ts2 = sm[4] + sm[5] + sm[6] + sm[7];
  float mean = ts * (1.0f / DIM_);
  float var  = ts2 * (1.0f / DIM_) - mean * mean;
  float rs = rsqrtf(var + 1e-5f);
  ushort4 o;
  o.x = f2b((f0 - mean) * rs * g0 + c0);
  o.y = f2b((f1 - mean) * rs * g1 + c1);
  o.z = f2b((f2 - mean) * rs * g2 + c2);
  o.w = f2b((f3 - mean) * rs * g3 + c3);
  ((ushort4*)(y + (size_t)row * DIM_))[t] = o;
}

// ---------------- merged transpose+cast of all 3 weights (grid.z selects) ------
__global__ void transpose3_kernel(const void* __restrict__ wq, unsigned short* __restrict__ wqt,
                                  const void* __restrict__ wkv, unsigned short* __restrict__ wkvt,
                                  const void* __restrict__ wo, unsigned short* __restrict__ wot,
                                  const int* __restrict__ flag) {
  const void* src; unsigned short* dst; int C;
  if (blockIdx.z == 0)      { src = wq;  dst = wqt;  C = 1024; }
  else if (blockIdx.z == 1) { src = wkv; dst = wkvt; C = 2048; }
  else                      { src = wo;  dst = wot;  C = 1024; }
  const int R = 1024;
  int bx = blockIdx.x * 32, by = blockIdx.y * 32;
  if (bx >= C) return;
  __shared__ unsigned short tile[32][33];
  int x = threadIdx.x, y = threadIdx.y;
  if (*flag) {
    const float* s = (const float*)src;
    for (int i = y; i < 32; i += 8) tile[i][x] = f2b(s[(size_t)(by + i) * C + bx + x]);
  } else {
    const unsigned short* s = (const unsigned short*)src;
    for (int i = y; i < 32; i += 8) tile[i][x] = s[(size_t)(by + i) * C + bx + x];
  }
  __syncthreads();
  for (int i = y; i < 32; i += 8) dst[(size_t)(bx + i) * R + by + x] = tile[x][i];
}

// ---------------- 128x128 MFMA GEMM core: dbuf + COUNTED vmcnt pipeline ------
// C[M,N] = A[M,K] @ Bt[N,K]^T (+bias). 256 threads, 4 waves in 2x2 over the tile.
// T4 (counted vmcnt, never drain to 0 mid-loop) + raw s_barrier: each tile's
// 4 DMAs/wave get a full iteration of flight time instead of being drained by
// __syncthreads' implicit vmcnt(0). Wait arithmetic (per wave, per iter i):
//   after STAGE(k+2): outstanding = {k+1:4, k+2:4}; vmcnt(4) -> k+1 landed.
//   tail (no STAGE issued): vmcnt(0) -> last tile landed.
__device__ __forceinline__ void gemm128_core(const unsigned short* __restrict__ A,
                                             const unsigned short* __restrict__ Bt,
                                             unsigned short* __restrict__ C,
                                             float* __restrict__ Cf,
                                             const unsigned short* __restrict__ bias,
                                             int bid, int mtiles, int M, int N, int K,
                                             bool f32o, int t) {
  __shared__ unsigned short As[2][128][32];
  __shared__ unsigned short Bs[2][128][32];
  int m0 = (bid % mtiles) * 128, n0 = (bid / mtiles) * 128;
  int wave = t >> 6, lane = t & 63;
  int wr = wave >> 1, wc = wave & 1;
  f32x4 acc[4][4];
  #pragma unroll
  for (int i = 0; i < 4; i++)
    #pragma unroll
    for (int j = 0; j < 4; j++)
      #pragma unroll
      for (int r = 0; r < 4; r++) acc[i][j][r] = 0.f;
  int lr = lane & 15, lk = (lane >> 4) * 8;
  // per-thread staging coordinates (chunk c = t, t+256; 8 bf16 per chunk)
  int row0 = t >> 2,         kc0 = (t & 3) * 8;
  int row1 = (t + 256) >> 2, kc1 = ((t + 256) & 3) * 8;
  const unsigned short* a0 = A  + (size_t)(m0 + row0) * K + kc0;
  const unsigned short* a1 = A  + (size_t)(m0 + row1) * K + kc1;
  const unsigned short* b0 = Bt + (size_t)(n0 + row0) * K + kc0;
  const unsigned short* b1 = Bt + (size_t)(n0 + row1) * K + kc1;
#define STAGE_(buf, koff) do { \
    gload_lds16(a0 + (koff), &As[buf][row0][kc0]); \
    gload_lds16(a1 + (koff), &As[buf][row1][kc1]); \
    gload_lds16(b0 + (koff), &Bs[buf][row0][kc0]); \
    gload_lds16(b1 + (koff), &Bs[buf][row1][kc1]); \
  } while (0)
  // prologue: tiles 0 and 1 in flight; wait only for tile 0 (4 newest remain)
  STAGE_(0, 0);
  STAGE_(1, 32);
  asm volatile("s_waitcnt vmcnt(4)" ::: "memory");
  __builtin_amdgcn_s_barrier();
  int cur = 0;
  for (int k0 = 0; k0 < K; k0 += 32) {
    bf16x8 af[4], bfr[4];
    #pragma unroll
    for (int i = 0; i < 4; i++) af[i]  = *(const bf16x8*)(&As[cur][wr * 64 + i * 16 + lr][lk]);
    #pragma unroll
    for (int j = 0; j < 4; j++) bfr[j] = *(const bf16x8*)(&Bs[cur][wc * 64 + j * 16 + lr][lk]);
    asm volatile("s_waitcnt lgkmcnt(0)" ::: "memory");   // frags in regs
    __builtin_amdgcn_sched_barrier(0);                   // rule 18: pin
    __builtin_amdgcn_s_barrier();                        // all waves done reading buf[cur]
    if (k0 + 64 < K) {
      STAGE_(cur, k0 + 64);                              // DMA tile k+2 into buf[cur]
      __builtin_amdgcn_sched_barrier(0);                 // keep DMA issue before MFMA
    }
    #pragma unroll
    for (int i = 0; i < 4; i++)
      #pragma unroll
      for (int j = 0; j < 4; j++)
        acc[i][j] = __builtin_amdgcn_mfma_f32_16x16x32_bf16(af[i], bfr[j], acc[i][j], 0, 0, 0);
    if (k0 + 64 < K) {
      asm volatile("s_waitcnt vmcnt(4)" ::: "memory");   // tile k+1 landed; k+2 flying
      __builtin_amdgcn_s_barrier();
    } else if (k0 + 32 < K) {
      asm volatile("s_waitcnt vmcnt(0)" ::: "memory");   // tail: last tile landed
      __builtin_amdgcn_s_barrier();
    }
    cur ^= 1;
  }
#undef STAGE_
  int rbase = (lane >> 4) * 4;
  int cbase = lane & 15;
  #pragma unroll
  for (int i = 0; i < 4; i++) {
    #pragma unroll
    for (int j = 0; j < 4; j++) {
      int row = m0 + wr * 64 + i * 16 + rbase;
      int col = n0 + wc * 64 + j * 16 + cbase;
      float bv = bias ? b2f(bias[col]) : 0.f;
      if (f32o) {
        #pragma unroll
        for (int r = 0; r < 4; r++)
          Cf[(size_t)(row + r) * N + col] = acc[i][j][r] + bv;
      } else {
        #pragma unroll
        for (int r = 0; r < 4; r++)
          C[(size_t)(row + r) * N + col] = f2b(acc[i][j][r] + bv);
      }
    }
  }
}

// fused q-GEMM (blocks [0,512): 64 mtiles x 8 ntiles) +
//       kv-GEMM (blocks [512,768): 16 mtiles x 16 ntiles = 256 blocks)
__global__ __launch_bounds__(256) void gemm_qkv(const unsigned short* __restrict__ tn,
                                                const unsigned short* __restrict__ wqt,
                                                unsigned short* __restrict__ qb,
                                                const unsigned short* __restrict__ mb,
                                                const unsigned short* __restrict__ wkvt,
                                                unsigned short* __restrict__ kvb) {
  int bid = blockIdx.x;
  if (bid < 512)
    gemm128_core(tn, wqt, qb, nullptr, nullptr, bid, 64, B_ * N_, DIM_, DIM_, false, threadIdx.x);
  else
    gemm128_core(mb, wkvt, kvb, nullptr, nullptr, bid - 512, 16, B_ * TN_, 2 * DIM_, DIM_, false, threadIdx.x);
}

__global__ __launch_bounds__(256) void gemm_out(const unsigned short* __restrict__ ao,
                                                const unsigned short* __restrict__ wot,
                                                unsigned short* __restrict__ C,
                                                float* __restrict__ Cf,
                                                const unsigned short* __restrict__ bias,
                                                const int* __restrict__ flag) {
  bool f32o = (*flag != 0);
  gemm128_core(ao, wot, C, Cf, bias, blockIdx.x, 64, B_ * N_, DIM_, DIM_, f32o, threadIdx.x);
}

// ---------------- MFMA attention: 1 wave per (b, 64-row tile, head) -------------
__global__ __launch_bounds__(64) void attn_mfma(const unsigned short* __restrict__ q,
                                                const unsigned short* __restrict__ kv,
                                                const int* __restrict__ tt,
                                                unsigned short* __restrict__ ao) {
  __shared__ unsigned short Vt[64][72];   // V^T [d][key]
  __shared__ unsigned short Ps[64][72];   // P [q][key]; reused as O staging
  int bid = blockIdx.x;
  int h  = bid & 15;
  int nt = (bid >> 4) & 31;
  int b  = bid >> 9;
  int bn0 = b * N_ + nt * 64;
  int lane = threadIdx.x & 63;
  int lr = lane & 15;
  int g  = lane >> 4;
  int g8 = g * 8;

  int tv = tt[bn0];             // tile-uniform by mask structure
  float vmul = (tv >= 1 && tv <= T_) ? 1.f : 0.f;
  int tvc = tv < 1 ? 1 : (tv > T_ ? T_ : tv);
  int kvrow0 = b * TN_ + (tvc - 1) * NL_;

  const unsigned short* vbase = kv + (size_t)kvrow0 * (2 * DIM_) + DIM_ + h * HD_;
  #pragma unroll
  for (int d0 = 0; d0 < 64; d0 += 8) {
    uint4 v = *(const uint4*)(vbase + (size_t)lane * (2 * DIM_) + d0);
    Vt[d0 + 0][lane] = (unsigned short)(v.x & 0xffff);
    Vt[d0 + 1][lane] = (unsigned short)(v.x >> 16);
    Vt[d0 + 2][lane] = (unsigned short)(v.y & 0xffff);
    Vt[d0 + 3][lane] = (unsigned short)(v.y >> 16);
    Vt[d0 + 4][lane] = (unsigned short)(v.z & 0xffff);
    Vt[d0 + 5][lane] = (unsigned short)(v.z >> 16);
    Vt[d0 + 6][lane] = (unsigned short)(v.w & 0xffff);
    Vt[d0 + 7][lane] = (unsigned short)(v.w >> 16);
  }

  f32x4 S[4][4];
  #pragma unroll
  for (int i = 0; i < 4; i++)
    #pragma unroll
    for (int j = 0; j < 4; j++)
      #pragma unroll
      for (int r = 0; r < 4; r++) S[i][j][r] = 0.f;
  #pragma unroll
  for (int ks = 0; ks < 2; ks++) {
    bf16x8 aQ[4], bK[4];
    #pragma unroll
    for (int mi = 0; mi < 4; mi++)
      aQ[mi] = *(const bf16x8*)(q + (size_t)(bn0 + mi * 16 + lr) * DIM_ + h * HD_ + ks * 32 + g8);
    #pragma unroll
    for (int ni = 0; ni < 4; ni++)
      bK[ni] = *(const bf16x8*)(kv + (size_t)(kvrow0 + ni * 16 + lr) * (2 * DIM_) + h * HD_ + ks * 32 + g8);
    #pragma unroll
    for (int mi = 0; mi < 4; mi++)
      #pragma unroll
      for (int ni = 0; ni < 4; ni++)
        S[mi][ni] = __builtin_amdgcn_mfma_f32_16x16x32_bf16(aQ[mi], bK[ni], S[mi][ni], 0, 0, 0);
  }

  #pragma unroll
  for (int mi = 0; mi < 4; mi++) {
    #pragma unroll
    for (int r = 0; r < 4; r++) {
      float mx = fmaxf(fmaxf(S[mi][0][r], S[mi][1][r]), fmaxf(S[mi][2][r], S[mi][3][r]));
      mx = fmaxf(mx, __shfl_xor(mx, 1));
      mx = fmaxf(mx, __shfl_xor(mx, 2));
      mx = fmaxf(mx, __shfl_xor(mx, 4));
      mx = fmaxf(mx, __shfl_xor(mx, 8));
      float e0 = __expf(S[mi][0][r] - mx);
      float e1 = __expf(S[mi][1][r] - mx);
      float e2 = __expf(S[mi][2][r] - mx);
      float e3 = __expf(S[mi][3][r] - mx);
      float sum = e0 + e1 + e2 + e3;
      sum += __shfl_xor(sum, 1);
      sum += __shfl_xor(sum, 2);
      sum += __shfl_xor(sum, 4);
      sum += __shfl_xor(sum, 8);
      float inv = 1.f / sum;
      int qrow = mi * 16 + g * 4 + r;
      Ps[qrow][ 0 + lr] = f2b(e0 * inv);
      Ps[qrow][16 + lr] = f2b(e1 * inv);
      Ps[qrow][32 + lr] = f2b(e2 * inv);
      Ps[qrow][48 + lr] = f2b(e3 * inv);
    }
  }
  __syncthreads();

  f32x4 O[4][4];
  #pragma unroll
  for (int i = 0; i < 4; i++)
    #pragma unroll
    for (int j = 0; j < 4; j++)
      #pragma unroll
      for (int r = 0; r < 4; r++) O[i][j][r] = 0.f;
  #pragma unroll
  for (int ks = 0; ks < 2; ks++) {
    bf16x8 aP[4], bV[4];
    #pragma unroll
    for (int mi = 0; mi < 4; mi++)
      aP[mi] = *(const bf16x8*)(&Ps[mi * 16 + lr][ks * 32 + g8]);
    #pragma unroll
    for (int ni = 0; ni < 4; ni++)
      bV[ni] = *(const bf16x8*)(&Vt[ni * 16 + lr][ks * 32 + g8]);
    #pragma unroll
    for (int mi = 0; mi < 4; mi++)
      #pragma unroll
      for (int ni = 0; ni < 4; ni++)
        O[mi][ni] = __builtin_amdgcn_mfma_f32_16x16x32_bf16(aP[mi], bV[ni], O[mi][ni], 0, 0, 0);
  }
  __syncthreads();

  #pragma unroll
  for (int mi = 0; mi < 4; mi++)
    #pragma unroll
    for (int ni = 0; ni < 4; ni++)
      #pragma unroll
      for (int r = 0; r < 4; r++)
        Ps[mi * 16 + g * 4 + r][ni * 16 + lr] = f2b(O[mi][ni][r] * vmul);
  __syncthreads();
  uint4* dst = (uint4*)(ao + (size_t)(bn0 + lane) * DIM_ + h * HD_);
  #pragma unroll
  for (int c = 0; c < 8; c++)
    dst[c] = *(const uint4*)(&Ps[lane][c * 8]);
}

extern "C" void kernel_launch(void* const* d_in, const int* in_sizes, int n_in,
                              void* d_out, int out_size, void* d_ws, size_t ws_size,
                              hipStream_t stream) {
  const void* text = d_in[0];
  const void* media = d_in[1];
  const void* mloc = d_in[2];
  const void* wq  = d_in[3];
  const void* wkv = d_in[4];
  const void* wo  = d_in[5];
  const void* bo  = d_in[6];
  const void* lng = d_in[7];
  const void* lnb = d_in[8];

  char* ws = (char*)d_ws;
  const size_t OFF_FLAG = (size_t)32 << 10;
  const size_t OFF_TN   = (size_t)64 << 10;
  const size_t OFF_WQT  = OFF_TN  + ((size_t)16 << 20) + ((size_t)64 << 10);
  const size_t OFF_WKVT = OFF_WQT + ((size_t)2 << 20);
  const size_t OFF_WOT  = OFF_WKVT + ((size_t)4 << 20);
  const size_t OFF_KV   = OFF_WOT + ((size_t)2 << 20);
  const size_t OFF_MB   = OFF_KV  + ((size_t)8 << 20);
  const size_t OFF_BO   = OFF_MB  + ((size_t)4 << 20);
  const size_t OFF_QB   = OFF_BO  + ((size_t)64 << 10);
  int* tt               = (int*)(ws + 0);
  int* flag             = (int*)(ws + OFF_FLAG);
  unsigned short* tn    = (unsigned short*)(ws + OFF_TN);
  unsigned short* ao    = tn;                               // reuse after q GEMM
  unsigned short* wqt   = (unsigned short*)(ws + OFF_WQT);
  unsigned short* wkvt  = (unsigned short*)(ws + OFF_WKVT);
  unsigned short* wot   = (unsigned short*)(ws + OFF_WOT);
  unsigned short* kvb   = (unsigned short*)(ws + OFF_KV);
  unsigned short* mb    = (unsigned short*)(ws + OFF_MB);
  unsigned short* bob   = (unsigned short*)(ws + OFF_BO);
  unsigned short* qb    = (unsigned short*)(ws + OFF_QB);

  detect_kernel<<<1, 256, 0, stream>>>((const unsigned short*)text, flag);
  times_kernel<<<B_, 256, 0, stream>>>(mloc, tt);
  ln_kernel<<<B_ * N_, 256, 0, stream>>>(text, lng, lnb, tn, flag);
  cast2_kernel<<<2049, 256, 0, stream>>>(media, mb, bo, bob, flag);
  transpose3_kernel<<<dim3(64, 32, 3), dim3(32, 8), 0, stream>>>(wq, wqt, wkv, wkvt, wo, wot, flag);

  // fused q (512 blocks, m-fastest) + kv (256 blocks) 128^2 counted-vmcnt GEMM
  gemm_qkv<<<768, 256, 0, stream>>>(tn, wqt, qb, mb, wkvt, kvb);
  // attention: 1 wave per (b, 64-row tile, head)
  attn_mfma<<<B_ * (N_/64) * H_, 64, 0, stream>>>(qb, kvb, tt, ao);
  // out = ao @ wo + bo (fp32 out if inputs fp32)
  gemm_out<<<512, 256, 0, stream>>>(ao, wot, (unsigned short*)d_out, (float*)d_out, bob, flag);
}

// Round 5
// 194.546 us; speedup vs baseline: 1.0861x; 1.0609x over previous
//
#include <hip/hip_runtime.h>
#include <stdint.h>

#define B_ 4
#define N_ 2048
#define T_ 8
#define NL_ 64
#define DIM_ 1024
#define H_ 16
#define HD_ 64
#define TN_ (T_*NL_)   // 512

typedef __bf16 bf16x8 __attribute__((ext_vector_type(8)));
typedef float f32x4 __attribute__((ext_vector_type(4)));

__device__ __forceinline__ float b2f(unsigned short x) {
  union { uint32_t u; float f; } v; v.u = ((uint32_t)x) << 16; return v.f;
}
__device__ __forceinline__ unsigned short f2b(float f) {
  union { float f; uint32_t u; } v; v.f = f;
  uint32_t r = v.u + 0x7FFFu + ((v.u >> 16) & 1u);
  return (unsigned short)(r >> 16);
}

// direct HBM->LDS DMA, 16B per lane (global_load_lds_dwordx4).
// LDS dest must be linear in lane id within the wave (m104 contract).
__device__ __forceinline__ void gload_lds16(const unsigned short* g, unsigned short* l) {
  __builtin_amdgcn_global_load_lds(
      (const __attribute__((address_space(1))) uint32_t*)g,
      (__attribute__((address_space(3))) uint32_t*)l, 16, 0, 0);
}

// ---------------- fp32-vs-bf16 storage detection ----------------
__global__ void detect_kernel(const unsigned short* __restrict__ text, int* __restrict__ flag) {
  int t = threadIdx.x;
  int bad = 0;
  #pragma unroll
  for (int i = 0; i < 16; i++) {
    unsigned short w = text[t * 16 + i];
    int e = (w >> 7) & 0xFF;
    if (e != 0 && (e < 90 || e > 150)) bad++;
  }
  __shared__ int red[256];
  red[t] = bad;
  __syncthreads();
  for (int o = 128; o > 0; o >>= 1) { if (t < o) red[t] += red[t + o]; __syncthreads(); }
  if (t == 0) flag[0] = (red[0] > 256) ? 1 : 0;   // 1 = fp32 storage
}

// ---------------- fused preprocessing: times + LN + media/bo cast + 3 transposes ----
// All four are independent given flag; fusing removes 3 full-device serialization
// points and lets the tiny times grid (4 blocks) overlap the big ones.
#define PREP_TIMES 4
#define PREP_LN    (B_*N_)     // 8192
#define PREP_CAST  2049
#define PREP_TR    4096        // wq:32x32=1024, wkv:64x32=2048, wo:1024

__global__ __launch_bounds__(256) void prep_kernel(
    const void* __restrict__ locs, int* __restrict__ tt,
    const void* __restrict__ text, const void* __restrict__ lng,
    const void* __restrict__ lnb, unsigned short* __restrict__ tn,
    const void* __restrict__ media, unsigned short* __restrict__ mb,
    const void* __restrict__ bo, unsigned short* __restrict__ bob,
    const void* __restrict__ wq, unsigned short* __restrict__ wqt,
    const void* __restrict__ wkv, unsigned short* __restrict__ wkvt,
    const void* __restrict__ wo, unsigned short* __restrict__ wot,
    const int* __restrict__ flag) {
  __shared__ __align__(16) unsigned char shraw[32 * 33 * 2];  // max of all users
  int gb = blockIdx.x;
  int t = threadIdx.x;

  if (gb < PREP_TIMES) {                      // ---- times (block scan) ----
    int* red = (int*)shraw;
    int b = gb;
    const unsigned char* p8 = (const unsigned char*)locs;
    const int* p32 = (const int*)locs;
    int cnt = 0;
    for (int i = t; i < B_*N_; i += 256) cnt += (p8[i] != 0) ? 1 : 0;
    red[t] = cnt;
    __syncthreads();
    for (int off = 128; off > 0; off >>= 1) {
      if (t < off) red[t] += red[t + off];
      __syncthreads();
    }
    int total = red[0];
    __syncthreads();
    bool isb = (total >= 2 * T_);
    int x[8];
    int base = b * N_ + t * 8;
    if (isb) {
      #pragma unroll
      for (int i = 0; i < 8; i++) x[i] = (int)(p8[base + i] != 0);
    } else {
      #pragma unroll
      for (int i = 0; i < 8; i++) x[i] = (int)(p32[base + i] != 0);
    }
    #pragma unroll
    for (int i = 1; i < 8; i++) x[i] += x[i-1];
    int tot = x[7];
    red[t] = tot;
    __syncthreads();
    for (int off = 1; off < 256; off <<= 1) {
      int v = (t >= off) ? red[t - off] : 0;
      __syncthreads();
      red[t] += v;
      __syncthreads();
    }
    int excl = red[t] - tot;
    #pragma unroll
    for (int i = 0; i < 8; i++) tt[base + i] = excl + x[i];
    return;
  }
  gb -= PREP_TIMES;

  if (gb < PREP_LN) {                         // ---- LayerNorm row ----
    float* sm = (float*)shraw;
    int row = gb;
    bool isf = (*flag != 0);
    float f0, f1, f2, f3, g0, g1, g2, g3, c0, c1, c2, c3;
    if (isf) {
      float4 xv = ((const float4*)text)[(size_t)row * (DIM_/4) + t];
      f0 = xv.x; f1 = xv.y; f2 = xv.z; f3 = xv.w;
      float4 gv = ((const float4*)lng)[t];
      g0 = gv.x; g1 = gv.y; g2 = gv.z; g3 = gv.w;
      float4 bv = ((const float4*)lnb)[t];
      c0 = bv.x; c1 = bv.y; c2 = bv.z; c3 = bv.w;
    } else {
      ushort4 xv = ((const ushort4*)text)[(size_t)row * (DIM_/4) + t];
      f0 = b2f(xv.x); f1 = b2f(xv.y); f2 = b2f(xv.z); f3 = b2f(xv.w);
      ushort4 gv = ((const ushort4*)lng)[t];
      g0 = b2f(gv.x); g1 = b2f(gv.y); g2 = b2f(gv.z); g3 = b2f(gv.w);
      ushort4 bv = ((const ushort4*)lnb)[t];
      c0 = b2f(bv.x); c1 = b2f(bv.y); c2 = b2f(bv.z); c3 = b2f(bv.w);
    }
    float s  = f0 + f1 + f2 + f3;
    float s2 = f0*f0 + f1*f1 + f2*f2 + f3*f3;
    for (int off = 32; off > 0; off >>= 1) { s += __shfl_xor(s, off); s2 += __shfl_xor(s2, off); }
    int wave = t >> 6, lane = t & 63;
    if (lane == 0) { sm[wave] = s; sm[wave + 4] = s2; }
    __syncthreads();
    float ts  = sm[0] + sm[1] + sm[2] + sm[3];
    float ts2 = sm[4] + sm[5] + sm[6] + sm[7];
    float mean = ts * (1.0f / DIM_);
    float var  = ts2 * (1.0f / DIM_) - mean * mean;
    float rs = rsqrtf(var + 1e-5f);
    ushort4 o;
    o.x = f2b((f0 - mean) * rs * g0 + c0);
    o.y = f2b((f1 - mean) * rs * g1 + c1);
    o.z = f2b((f2 - mean) * rs * g2 + c2);
    o.w = f2b((f3 - mean) * rs * g3 + c3);
    ((ushort4*)(tn + (size_t)row * DIM_))[t] = o;
    return;
  }
  gb -= PREP_LN;

  if (gb < PREP_CAST) {                       // ---- media + bo cast ----
    const int N4M = (B_*T_*NL_*DIM_) / 4;     // 524288
    int i = gb * 256 + t;
    bool isf = (*flag != 0);
    if (i < N4M) {
      ushort4 o;
      if (isf) {
        float4 v = ((const float4*)media)[i];
        o.x = f2b(v.x); o.y = f2b(v.y); o.z = f2b(v.z); o.w = f2b(v.w);
      } else {
        o = ((const ushort4*)media)[i];
      }
      ((ushort4*)mb)[i] = o;
    } else {
      int j = i - N4M;
      if (j < DIM_/4) {
        ushort4 o;
        if (isf) {
          float4 v = ((const float4*)bo)[j];
          o.x = f2b(v.x); o.y = f2b(v.y); o.z = f2b(v.z); o.w = f2b(v.w);
        } else {
          o = ((const ushort4*)bo)[j];
        }
        ((ushort4*)bob)[j] = o;
      }
    }
    return;
  }
  gb -= PREP_CAST;

  {                                           // ---- weight transpose+cast ----
    unsigned short (*tile)[33] = (unsigned short (*)[33])shraw;
    const void* src; unsigned short* dst; int C, zz, nx;
    if (gb < 1024)      { src = wq;  dst = wqt;  C = 1024; zz = gb;        nx = 32; }
    else if (gb < 3072) { src = wkv; dst = wkvt; C = 2048; zz = gb - 1024; nx = 64; }
    else                { src = wo;  dst = wot;  C = 1024; zz = gb - 3072; nx = 32; }
    const int R = 1024;
    int xi = zz % nx, yi = zz / nx;
    int bx = xi * 32, by = yi * 32;
    int x = t & 31, y = t >> 5;
    if (*flag) {
      const float* s = (const float*)src;
      for (int i = y; i < 32; i += 8) tile[i][x] = f2b(s[(size_t)(by + i) * C + bx + x]);
    } else {
      const unsigned short* s = (const unsigned short*)src;
      for (int i = y; i < 32; i += 8) tile[i][x] = s[(size_t)(by + i) * C + bx + x];
    }
    __syncthreads();
    for (int i = y; i < 32; i += 8) dst[(size_t)(bx + i) * R + by + x] = tile[x][i];
  }
}

// ---------------- 128x128 MFMA GEMM core: depth-3 counted-vmcnt pipeline ------
// C[M,N] = A[M,K] @ Bt[N,K]^T (+bias). 256 threads, 4 waves in 2x2 over the tile.
// 3 LDS buffers (48 KB), tiles T(i+1),T(i+2),T(i+3) in flight -> each DMA gets
// ~2 iterations of flight (covers L3/HBM ~500-900 cyc). vmcnt arithmetic per
// wave (4 DMAs per tile): after STAGE(T(i+3)) outstanding = 12 -> vmcnt(8)
// guarantees oldest group T(i+1) landed. Tails: 4 -> 0. Requires K >= 96.
__device__ __forceinline__ void gemm128_core(const unsigned short* __restrict__ A,
                                             const unsigned short* __restrict__ Bt,
                                             unsigned short* __restrict__ C,
                                             float* __restrict__ Cf,
                                             const unsigned short* __restrict__ bias,
                                             int bid, int mtiles, int M, int N, int K,
                                             bool f32o, int t) {
  __shared__ unsigned short As[3][128][32];
  __shared__ unsigned short Bs[3][128][32];
  int m0 = (bid % mtiles) * 128, n0 = (bid / mtiles) * 128;
  int wave = t >> 6, lane = t & 63;
  int wr = wave >> 1, wc = wave & 1;
  f32x4 acc[4][4];
  #pragma unroll
  for (int i = 0; i < 4; i++)
    #pragma unroll
    for (int j = 0; j < 4; j++)
      #pragma unroll
      for (int r = 0; r < 4; r++) acc[i][j][r] = 0.f;
  int lr = lane & 15, lk = (lane >> 4) * 8;
  // per-thread staging coordinates (chunk c = t, t+256; 8 bf16 per chunk)
  int row0 = t >> 2,         kc0 = (t & 3) * 8;
  int row1 = (t + 256) >> 2, kc1 = ((t + 256) & 3) * 8;
  const unsigned short* a0 = A  + (size_t)(m0 + row0) * K + kc0;
  const unsigned short* a1 = A  + (size_t)(m0 + row1) * K + kc1;
  const unsigned short* b0 = Bt + (size_t)(n0 + row0) * K + kc0;
  const unsigned short* b1 = Bt + (size_t)(n0 + row1) * K + kc1;
#define STAGE_(buf, koff) do { \
    gload_lds16(a0 + (koff), &As[buf][row0][kc0]); \
    gload_lds16(a1 + (koff), &As[buf][row1][kc1]); \
    gload_lds16(b0 + (koff), &Bs[buf][row0][kc0]); \
    gload_lds16(b1 + (koff), &Bs[buf][row1][kc1]); \
  } while (0)
  // prologue: T0,T1,T2 in flight (12 DMAs/wave); wait T0 (8 newest remain)
  STAGE_(0, 0);
  STAGE_(1, 32);
  STAGE_(2, 64);
  asm volatile("s_waitcnt vmcnt(8)" ::: "memory");
  __builtin_amdgcn_s_barrier();
  int cur = 0;
  for (int k0 = 0; k0 < K; k0 += 32) {
    bf16x8 af[4], bfr[4];
    #pragma unroll
    for (int i = 0; i < 4; i++) af[i]  = *(const bf16x8*)(&As[cur][wr * 64 + i * 16 + lr][lk]);
    #pragma unroll
    for (int j = 0; j < 4; j++) bfr[j] = *(const bf16x8*)(&Bs[cur][wc * 64 + j * 16 + lr][lk]);
    asm volatile("s_waitcnt lgkmcnt(0)" ::: "memory");   // frags in regs
    __builtin_amdgcn_sched_barrier(0);                   // rule 18: pin
    __builtin_amdgcn_s_barrier();                        // all waves done reading buf[cur]
    if (k0 + 96 < K) {
      STAGE_(cur, k0 + 96);                              // DMA tile T(i+3) into freed buf
      __builtin_amdgcn_sched_barrier(0);                 // keep DMA issue before MFMA
    }
    #pragma unroll
    for (int i = 0; i < 4; i++)
      #pragma unroll
      for (int j = 0; j < 4; j++)
        acc[i][j] = __builtin_amdgcn_mfma_f32_16x16x32_bf16(af[i], bfr[j], acc[i][j], 0, 0, 0);
    if (k0 + 96 < K) {
      asm volatile("s_waitcnt vmcnt(8)" ::: "memory");   // T(i+1) landed; T(i+2,3) flying
      __builtin_amdgcn_s_barrier();
    } else if (k0 + 64 < K) {
      asm volatile("s_waitcnt vmcnt(4)" ::: "memory");   // T(i+1) landed; T(i+2) flying
      __builtin_amdgcn_s_barrier();
    } else if (k0 + 32 < K) {
      asm volatile("s_waitcnt vmcnt(0)" ::: "memory");   // tail: last tile landed
      __builtin_amdgcn_s_barrier();
    }
    cur = (cur == 2) ? 0 : cur + 1;
  }
#undef STAGE_
  int rbase = (lane >> 4) * 4;
  int cbase = lane & 15;
  #pragma unroll
  for (int i = 0; i < 4; i++) {
    #pragma unroll
    for (int j = 0; j < 4; j++) {
      int row = m0 + wr * 64 + i * 16 + rbase;
      int col = n0 + wc * 64 + j * 16 + cbase;
      float bv = bias ? b2f(bias[col]) : 0.f;
      if (f32o) {
        #pragma unroll
        for (int r = 0; r < 4; r++)
          Cf[(size_t)(row + r) * N + col] = acc[i][j][r] + bv;
      } else {
        #pragma unroll
        for (int r = 0; r < 4; r++)
          C[(size_t)(row + r) * N + col] = f2b(acc[i][j][r] + bv);
      }
    }
  }
}

// fused q-GEMM (blocks [0,512): 64 mtiles x 8 ntiles) +
//       kv-GEMM (blocks [512,768): 16 mtiles x 16 ntiles = 256 blocks)
__global__ __launch_bounds__(256) void gemm_qkv(const unsigned short* __restrict__ tn,
                                                const unsigned short* __restrict__ wqt,
                                                unsigned short* __restrict__ qb,
                                                const unsigned short* __restrict__ mb,
                                                const unsigned short* __restrict__ wkvt,
                                                unsigned short* __restrict__ kvb) {
  int bid = blockIdx.x;
  if (bid < 512)
    gemm128_core(tn, wqt, qb, nullptr, nullptr, bid, 64, B_ * N_, DIM_, DIM_, false, threadIdx.x);
  else
    gemm128_core(mb, wkvt, kvb, nullptr, nullptr, bid - 512, 16, B_ * TN_, 2 * DIM_, DIM_, false, threadIdx.x);
}

__global__ __launch_bounds__(256) void gemm_out(const unsigned short* __restrict__ ao,
                                                const unsigned short* __restrict__ wot,
                                                unsigned short* __restrict__ C,
                                                float* __restrict__ Cf,
                                                const unsigned short* __restrict__ bias,
                                                const int* __restrict__ flag) {
  bool f32o = (*flag != 0);
  gemm128_core(ao, wot, C, Cf, bias, blockIdx.x, 64, B_ * N_, DIM_, DIM_, f32o, threadIdx.x);
}

// ---------------- MFMA attention: 1 wave per (b, 64-row tile, head) -------------
__global__ __launch_bounds__(64) void attn_mfma(const unsigned short* __restrict__ q,
                                                const unsigned short* __restrict__ kv,
                                                const int* __restrict__ tt,
                                                unsigned short* __restrict__ ao) {
  __shared__ unsigned short Vt[64][72];   // V^T [d][key]
  __shared__ unsigned short Ps[64][72];   // P [q][key]; reused as O staging
  int bid = blockIdx.x;
  int h  = bid & 15;
  int nt = (bid >> 4) & 31;
  int b  = bid >> 9;
  int bn0 = b * N_ + nt * 64;
  int lane = threadIdx.x & 63;
  int lr = lane & 15;
  int g  = lane >> 4;
  int g8 = g * 8;

  int tv = tt[bn0];             // tile-uniform by mask structure
  float vmul = (tv >= 1 && tv <= T_) ? 1.f : 0.f;
  int tvc = tv < 1 ? 1 : (tv > T_ ? T_ : tv);
  int kvrow0 = b * TN_ + (tvc - 1) * NL_;

  const unsigned short* vbase = kv + (size_t)kvrow0 * (2 * DIM_) + DIM_ + h * HD_;
  #pragma unroll
  for (int d0 = 0; d0 < 64; d0 += 8) {
    uint4 v = *(const uint4*)(vbase + (size_t)lane * (2 * DIM_) + d0);
    Vt[d0 + 0][lane] = (unsigned short)(v.x & 0xffff);
    Vt[d0 + 1][lane] = (unsigned short)(v.x >> 16);
    Vt[d0 + 2][lane] = (unsigned short)(v.y & 0xffff);
    Vt[d0 + 3][lane] = (unsigned short)(v.y >> 16);
    Vt[d0 + 4][lane] = (unsigned short)(v.z & 0xffff);
    Vt[d0 + 5][lane] = (unsigned short)(v.z >> 16);
    Vt[d0 + 6][lane] = (unsigned short)(v.w & 0xffff);
    Vt[d0 + 7][lane] = (unsigned short)(v.w >> 16);
  }

  f32x4 S[4][4];
  #pragma unroll
  for (int i = 0; i < 4; i++)
    #pragma unroll
    for (int j = 0; j < 4; j++)
      #pragma unroll
      for (int r = 0; r < 4; r++) S[i][j][r] = 0.f;
  #pragma unroll
  for (int ks = 0; ks < 2; ks++) {
    bf16x8 aQ[4], bK[4];
    #pragma unroll
    for (int mi = 0; mi < 4; mi++)
      aQ[mi] = *(const bf16x8*)(q + (size_t)(bn0 + mi * 16 + lr) * DIM_ + h * HD_ + ks * 32 + g8);
    #pragma unroll
    for (int ni = 0; ni < 4; ni++)
      bK[ni] = *(const bf16x8*)(kv + (size_t)(kvrow0 + ni * 16 + lr) * (2 * DIM_) + h * HD_ + ks * 32 + g8);
    #pragma unroll
    for (int mi = 0; mi < 4; mi++)
      #pragma unroll
      for (int ni = 0; ni < 4; ni++)
        S[mi][ni] = __builtin_amdgcn_mfma_f32_16x16x32_bf16(aQ[mi], bK[ni], S[mi][ni], 0, 0, 0);
  }

  #pragma unroll
  for (int mi = 0; mi < 4; mi++) {
    #pragma unroll
    for (int r = 0; r < 4; r++) {
      float mx = fmaxf(fmaxf(S[mi][0][r], S[mi][1][r]), fmaxf(S[mi][2][r], S[mi][3][r]));
      mx = fmaxf(mx, __shfl_xor(mx, 1));
      mx = fmaxf(mx, __shfl_xor(mx, 2));
      mx = fmaxf(mx, __shfl_xor(mx, 4));
      mx = fmaxf(mx, __shfl_xor(mx, 8));
      float e0 = __expf(S[mi][0][r] - mx);
      float e1 = __expf(S[mi][1][r] - mx);
      float e2 = __expf(S[mi][2][r] - mx);
      float e3 = __expf(S[mi][3][r] - mx);
      float sum = e0 + e1 + e2 + e3;
      sum += __shfl_xor(sum, 1);
      sum += __shfl_xor(sum, 2);
      sum += __shfl_xor(sum, 4);
      sum += __shfl_xor(sum, 8);
      float inv = 1.f / sum;
      int qrow = mi * 16 + g * 4 + r;
      Ps[qrow][ 0 + lr] = f2b(e0 * inv);
      Ps[qrow][16 + lr] = f2b(e1 * inv);
      Ps[qrow][32 + lr] = f2b(e2 * inv);
      Ps[qrow][48 + lr] = f2b(e3 * inv);
    }
  }
  __syncthreads();

  f32x4 O[4][4];
  #pragma unroll
  for (int i = 0; i < 4; i++)
    #pragma unroll
    for (int j = 0; j < 4; j++)
      #pragma unroll
      for (int r = 0; r < 4; r++) O[i][j][r] = 0.f;
  #pragma unroll
  for (int ks = 0; ks < 2; ks++) {
    bf16x8 aP[4], bV[4];
    #pragma unroll
    for (int mi = 0; mi < 4; mi++)
      aP[mi] = *(const bf16x8*)(&Ps[mi * 16 + lr][ks * 32 + g8]);
    #pragma unroll
    for (int ni = 0; ni < 4; ni++)
      bV[ni] = *(const bf16x8*)(&Vt[ni * 16 + lr][ks * 32 + g8]);
    #pragma unroll
    for (int mi = 0; mi < 4; mi++)
      #pragma unroll
      for (int ni = 0; ni < 4; ni++)
        O[mi][ni] = __builtin_amdgcn_mfma_f32_16x16x32_bf16(aP[mi], bV[ni], O[mi][ni], 0, 0, 0);
  }
  __syncthreads();

  #pragma unroll
  for (int mi = 0; mi < 4; mi++)
    #pragma unroll
    for (int ni = 0; ni < 4; ni++)
      #pragma unroll
      for (int r = 0; r < 4; r++)
        Ps[mi * 16 + g * 4 + r][ni * 16 + lr] = f2b(O[mi][ni][r] * vmul);
  __syncthreads();
  uint4* dst = (uint4*)(ao + (size_t)(bn0 + lane) * DIM_ + h * HD_);
  #pragma unroll
  for (int c = 0; c < 8; c++)
    dst[c] = *(const uint4*)(&Ps[lane][c * 8]);
}

extern "C" void kernel_launch(void* const* d_in, const int* in_sizes, int n_in,
                              void* d_out, int out_size, void* d_ws, size_t ws_size,
                              hipStream_t stream) {
  const void* text = d_in[0];
  const void* media = d_in[1];
  const void* mloc = d_in[2];
  const void* wq  = d_in[3];
  const void* wkv = d_in[4];
  const void* wo  = d_in[5];
  const void* bo  = d_in[6];
  const void* lng = d_in[7];
  const void* lnb = d_in[8];

  char* ws = (char*)d_ws;
  const size_t OFF_FLAG = (size_t)32 << 10;
  const size_t OFF_TN   = (size_t)64 << 10;
  const size_t OFF_WQT  = OFF_TN  + ((size_t)16 << 20) + ((size_t)64 << 10);
  const size_t OFF_WKVT = OFF_WQT + ((size_t)2 << 20);
  const size_t OFF_WOT  = OFF_WKVT + ((size_t)4 << 20);
  const size_t OFF_KV   = OFF_WOT + ((size_t)2 << 20);
  const size_t OFF_MB   = OFF_KV  + ((size_t)8 << 20);
  const size_t OFF_BO   = OFF_MB  + ((size_t)4 << 20);
  const size_t OFF_QB   = OFF_BO  + ((size_t)64 << 10);
  int* tt               = (int*)(ws + 0);
  int* flag             = (int*)(ws + OFF_FLAG);
  unsigned short* tn    = (unsigned short*)(ws + OFF_TN);
  unsigned short* ao    = tn;                               // reuse after q GEMM
  unsigned short* wqt   = (unsigned short*)(ws + OFF_WQT);
  unsigned short* wkvt  = (unsigned short*)(ws + OFF_WKVT);
  unsigned short* wot   = (unsigned short*)(ws + OFF_WOT);
  unsigned short* kvb   = (unsigned short*)(ws + OFF_KV);
  unsigned short* mb    = (unsigned short*)(ws + OFF_MB);
  unsigned short* bob   = (unsigned short*)(ws + OFF_BO);
  unsigned short* qb    = (unsigned short*)(ws + OFF_QB);

  detect_kernel<<<1, 256, 0, stream>>>((const unsigned short*)text, flag);
  // fused prep: times + LN + media/bo cast + weight transposes (one launch)
  prep_kernel<<<PREP_TIMES + PREP_LN + PREP_CAST + PREP_TR, 256, 0, stream>>>(
      mloc, tt, text, lng, lnb, tn, media, mb, bo, bob,
      wq, wqt, wkv, wkvt, wo, wot, flag);

  // fused q (512 blocks, m-fastest) + kv (256 blocks) 128^2 depth-3 GEMM
  gemm_qkv<<<768, 256, 0, stream>>>(tn, wqt, qb, mb, wkvt, kvb);
  // attention: 1 wave per (b, 64-row tile, head)
  attn_mfma<<<B_ * (N_/64) * H_, 64, 0, stream>>>(qb, kvb, tt, ao);
  // out = ao @ wo + bo (fp32 out if inputs fp32)
  gemm_out<<<512, 256, 0, stream>>>(ao, wot, (unsigned short*)d_out, (float*)d_out, bob, flag);
}